// Round 13
// baseline (1294.825 us; speedup 1.0000x reference)
//
#include <hip/hip_runtime.h>
#include <stdint.h>

#define TT 512

typedef __fp16   f16x8  __attribute__((ext_vector_type(8)));
typedef float    f32x4  __attribute__((ext_vector_type(4)));
typedef __fp16   fp16x2 __attribute__((ext_vector_type(2)));
typedef uint32_t u32x2  __attribute__((ext_vector_type(2)));

__device__ __forceinline__ f32x4 mfma16(f16x8 a, f16x8 b, f32x4 c) {
    return __builtin_amdgcn_mfma_f32_16x16x32_f16(a, b, c, 0, 0, 0);
}
__device__ __forceinline__ uint32_t pkf16(float a, float b) {
    fp16x2 h = __builtin_amdgcn_cvt_pkrtz(a, b);
    return __builtin_bit_cast(uint32_t, h);
}

#define REP8(M) M(0)M(1)M(2)M(3)M(4)M(5)M(6)M(7)

// A-operand gather (weights transposed, z^T form): A[m=16T+l15][k=32F+8q+j] = SRC[k][16T+l15]
#define GA(SRC, T, F) (f16x8){ \
  (__fp16)(SRC)[(32*(F)+8*quad+0)*256 + 16*(T)+l15], \
  (__fp16)(SRC)[(32*(F)+8*quad+1)*256 + 16*(T)+l15], \
  (__fp16)(SRC)[(32*(F)+8*quad+2)*256 + 16*(T)+l15], \
  (__fp16)(SRC)[(32*(F)+8*quad+3)*256 + 16*(T)+l15], \
  (__fp16)(SRC)[(32*(F)+8*quad+4)*256 + 16*(T)+l15], \
  (__fp16)(SRC)[(32*(F)+8*quad+5)*256 + 16*(T)+l15], \
  (__fp16)(SRC)[(32*(F)+8*quad+6)*256 + 16*(T)+l15], \
  (__fp16)(SRC)[(32*(F)+8*quad+7)*256 + 16*(T)+l15] }

// Wave (l,h) owns zcols {64g + 32h + 16q' .. +15}: local j = 2g+q' -> global tile:
#define DECLT(j) f16x8 uA##j##_0, uA##j##_1, wA##j##_0, wA##j##_1; f32x4 bias##j;
#define LOADT(j) { \
  const int Tg_ = ((j)>>1)*4 + 2*h + ((j)&1); \
  uA##j##_0 = GA(Uw, Tg_, 0); uA##j##_1 = GA(Uw, Tg_, 1); \
  bias##j = (f32x4){ bw_[16*Tg_ + 4*quad + 0], bw_[16*Tg_ + 4*quad + 1], \
                     bw_[16*Tg_ + 4*quad + 2], bw_[16*Tg_ + 4*quad + 3] }; \
  if (l > 0) { wA##j##_0 = GA(Wsrc, Tg_, 0); wA##j##_1 = GA(Wsrc, Tg_, 1); } \
  else { wA##j##_0 = __builtin_bit_cast(f16x8, (f32x4){ \
           Wx0[16*Tg_+4*quad+0], Wx0[16*Tg_+4*quad+1], \
           Wx0[16*Tg_+4*quad+2], Wx0[16*Tg_+4*quad+3] }); \
         wA##j##_1 = wA##j##_0; } }

// MFMA segment: W-side first (xBp register-prefetched, bias rides C), U-side last.
#define MW0(j) acc##j = mfma16(wA##j##_0, xBp0, bias##j);
#define MW1(j) acc##j = mfma16(wA##j##_1, xBp1, acc##j);
#define MX(j)  acc##j = bias##j + __builtin_bit_cast(f32x4, wA##j##_0) * xvp4;
#define MU0(j) acc##j = mfma16(uA##j##_0, hB0, acc##j);
#define MU1(j) acc##j = mfma16(uA##j##_1, hB1, acc##j);

#define MFMA_SEG(t_) { \
  const __fp16* hp_ = hb_l + (((t_)-1)&3)*1152 + l15*72 + 8*quad; \
  f16x8 hB0 = *(const f16x8*)hp_; \
  f16x8 hB1 = *(const f16x8*)(hp_ + 32); \
  if (l > 0) { REP8(MW0) REP8(MW1) } \
  else       { f32x4 xvp4 = {xvp, xvp, xvp, xvp}; REP8(MX) } \
  REP8(MU0) \
  REP8(MU1) }

// Gates: trans batched (exp burst, rcp burst), vector f32x4 tail -> pk ops.
#define GATES(qp, Ai, Af, Ag, Ao, CST, SAVEK, HK) { \
  f32x4 ei_, ef_, eo_; \
  _Pragma("unroll") for (int r_ = 0; r_ < 4; ++r_) { \
    ei_[r_] = __builtin_amdgcn_exp2f(-1.4426950408889634f * Ai[r_]); \
    ef_[r_] = __builtin_amdgcn_exp2f(-1.4426950408889634f * Af[r_]); \
    eo_[r_] = __builtin_amdgcn_exp2f(-1.4426950408889634f * Ao[r_]); \
  } \
  f32x4 si_, sf_, so_; \
  _Pragma("unroll") for (int r_ = 0; r_ < 4; ++r_) { \
    si_[r_] = __builtin_amdgcn_rcpf(1.0f + ei_[r_]); \
    sf_[r_] = __builtin_amdgcn_rcpf(1.0f + ef_[r_]); \
    so_[r_] = __builtin_amdgcn_rcpf(1.0f + eo_[r_]); \
  } \
  const f32x4 z4_ = {0.f, 0.f, 0.f, 0.f}; \
  f32x4 rg_ = __builtin_elementwise_max(Ag, z4_); \
  f32x4 cv_ = sf_ * CST + si_ * rg_; \
  CST = cv_; \
  f32x4 hv_ = so_ * __builtin_elementwise_max(cv_, z4_); \
  u32x2 pv_ = { pkf16(hv_[0], hv_[1]), pkf16(hv_[2], hv_[3]) }; \
  *(u32x2*)(hw_ + 16*(qp)) = pv_; \
  if (SAVEK) HK = hv_; }

#define GATE_SEG(tg_, SV_) { \
  __fp16* hw_ = hb_l + ((tg_)&3)*1152 + l15*72 + 32*h + 4*quad; \
  GATES(0, acc0, acc2, acc4, acc6, cst0, SV_, hK0) \
  GATES(1, acc1, acc3, acc5, acc7, cst1, SV_, hK1) }

// R13: 512 blocks x 2 batch rows (was 64 x 16). R11-vs-R12 arithmetic showed the
// wall is work-proportional with ~6x issue-time multiplier at 2 waves/SIMD:
// exposed per-instruction latency, not pipe or barrier cost. Fix = TLP: VGPR=128
// allows 4 waves/SIMD = TWO 8-wave blocks co-resident per CU (LDS cut to 44 KB),
// so two independent recurrence pipelines interleave and hide each other's
// latencies (R6 at 4 waves/SIMD sustained 62% VALUBusy; this shape sits at 16%).
// MFMA M=16 with 2 real rows wastes matrix throughput - irrelevant at 7% util.
// Lanes l15>=2 compute duplicates of rows 0/1 (finite, never mix into real cols).
// Everything else identical to R12 (anti-phase, skew-2, reg-prefetch, pk-gates).
__global__ __launch_bounds__(512)
__attribute__((amdgpu_waves_per_eu(2, 2)))
void lstm_phase(
    const float* __restrict__ x,
    const float* __restrict__ Wx0, const float* __restrict__ U0, const float* __restrict__ b0,
    const float* __restrict__ Wx1, const float* __restrict__ U1, const float* __restrict__ b1,
    const float* __restrict__ Wx2, const float* __restrict__ U2, const float* __restrict__ b2,
    const float* __restrict__ Wx3, const float* __restrict__ U3, const float* __restrict__ b3,
    const float* __restrict__ Wd,  const float* __restrict__ bd,
    float* __restrict__ out)
{
    // dwords: hbuf f16 [0,9216) | x_s f32 [9216,11264) | red f32 [11264,11296)
    extern __shared__ uint32_t smem[];
    __fp16* hb16 = (__fp16*)smem;              // [l][slot4][row 16][unit 64 pad 72]
    float*  xs   = (float*)(smem + 9216);      // [t][4] (rows 0..1 real)
    float*  red  = (float*)(smem + 11264);     // [2][16] epilogue partials

    const int tid  = threadIdx.x;
    const int lane = tid & 63;
    const int l15  = lane & 15;
    const int quad = lane >> 4;
    const int wv   = tid >> 6;
    const int l    = wv >> 1;                  // layer
    const int h    = wv & 1;                   // unit-half
    const int b0i  = blockIdx.x * 2;
    const bool phA = (l < 2);

    // ---- staging ----
    for (int i = tid; i < 9216; i += 512) smem[i] = 0;       // zero all h slots
    for (int i = tid; i < 2 * TT; i += 512) {
        int row = i & 1, t_ = i >> 1;
        xs[t_ * 4 + row] = x[(b0i + row) * TT + t_];
    }

    const float* Uw   = (l == 0) ? U0 : (l == 1) ? U1 : (l == 2) ? U2 : U3;
    const float* bw_  = (l == 0) ? b0 : (l == 1) ? b1 : (l == 2) ? b2 : b3;
    const float* Wsrc = (l == 1) ? Wx1 : (l == 2) ? Wx2 : (l == 3) ? Wx3 : U0;

    REP8(DECLT)
    REP8(LOADT)

    f32x4 acc0, acc1, acc2, acc3, acc4, acc5, acc6, acc7;    // persist across barriers
    f32x4 cst0 = {0,0,0,0}, cst1 = {0,0,0,0};
    f32x4 hK0  = {0,0,0,0}, hK1  = {0,0,0,0};

    __fp16* hb_l  = hb16 + l * 4608;           // own buffer (4 slots x 1152 f16)
    const __fp16* hb_in = hb16 + (l > 0 ? (l - 1) * 4608 : 0);

    f16x8 xBp0 = {}, xBp1 = {};                // register-prefetched x-side operands
    float xvp = 0.f;

    __syncthreads();

    if (l == 0) xvp = xs[l15 & 1];             // layer-0 prefetch for t=0 (lanes>=2 dup row 0/1)

    for (int s = 0; s < TT + 8; ++s) {
        // ---------------- SEG1 ----------------
        if (phA) {
            const int t = s - 2 * l;
            if (t >= 0 && t < TT) MFMA_SEG(t)
        } else {
            // prefetch first (latency overlaps gate compute below)
            const int tm = s - 2 * l;          // step whose MFMA runs in SEG2
            if (tm >= 0 && tm < TT) {
                const __fp16* xp_ = hb_in + (tm & 3) * 1152 + l15 * 72 + 8 * quad;
                xBp0 = *(const f16x8*)xp_;
                xBp1 = *(const f16x8*)(xp_ + 32);
            }
            const int tg = s - 1 - 2 * l;      // gates of last interval's accs
            if (tg >= 0 && tg < TT) {
                const bool sv_ = (l == 3) && (tg == TT - 1);
                GATE_SEG(tg, sv_)
            }
        }
        __syncthreads();
        // ---------------- SEG2 ----------------
        if (phA) {
            // prefetch first
            const int tn = s + 1 - 2 * l;      // step whose MFMA runs next SEG1
            if (tn >= 0 && tn < TT) {
                if (l > 0) {
                    const __fp16* xp_ = hb_in + (tn & 3) * 1152 + l15 * 72 + 8 * quad;
                    xBp0 = *(const f16x8*)xp_;
                    xBp1 = *(const f16x8*)(xp_ + 32);
                } else {
                    xvp = xs[tn * 4 + (l15 & 1)];
                }
            }
            const int t = s - 2 * l;
            if (t >= 0 && t < TT) GATE_SEG(t, false)
        } else {
            const int t = s - 2 * l;
            if (t >= 0 && t < TT) MFMA_SEG(t)
        }
        __syncthreads();
    }

    // dense epilogue: waves (3,h); lane holds h[511] f32 for units 32h+16q'+4quad+r, row l15
    if (l == 3) {
        float p = 0.f;
        #pragma unroll
        for (int r = 0; r < 4; ++r) {
            p += hK0[r] * Wd[32 * h + 4 * quad + r];
            p += hK1[r] * Wd[32 * h + 16 + 4 * quad + r];
        }
        p += __shfl_down(p, 32, 64);
        p += __shfl_down(p, 16, 64);
        if (lane < 16) red[h * 16 + lane] = p;
    }
    __syncthreads();
    if (wv == 6 && lane < 2) out[b0i + lane] = red[lane] + red[16 + lane] + bd[0];
}

extern "C" void kernel_launch(void* const* d_in, const int* in_sizes, int n_in,
                              void* d_out, int out_size, void* d_ws, size_t ws_size,
                              hipStream_t stream) {
    const float* x   = (const float*)d_in[0];
    const float* Wx0 = (const float*)d_in[1];
    const float* U0  = (const float*)d_in[2];
    const float* b0  = (const float*)d_in[3];
    const float* Wx1 = (const float*)d_in[4];
    const float* U1  = (const float*)d_in[5];
    const float* b1  = (const float*)d_in[6];
    const float* Wx2 = (const float*)d_in[7];
    const float* U2  = (const float*)d_in[8];
    const float* b2  = (const float*)d_in[9];
    const float* Wx3 = (const float*)d_in[10];
    const float* U3  = (const float*)d_in[11];
    const float* b3  = (const float*)d_in[12];
    const float* Wd  = (const float*)d_in[13];
    const float* bd  = (const float*)d_in[14];
    float* out = (float*)d_out;

    static const int kLds = 11296 * 4;   // 45184 B dynamic LDS -> 2 blocks/CU
    (void)hipFuncSetAttribute((const void*)lstm_phase,
                              hipFuncAttributeMaxDynamicSharedMemorySize, kLds);
    hipLaunchKernelGGL(lstm_phase, dim3(512), dim3(512), kLds, stream,
                       x, Wx0, U0, b0, Wx1, U1, b1, Wx2, U2, b2, Wx3, U3, b3,
                       Wd, bd, out);
}